// Round 13
// baseline (126.039 us; speedup 1.0000x reference)
//
#include <hip/hip_runtime.h>

// B=4, P=2048, N=8192, QD=CD=INNER=512, HEADS=8, DH=64, HC=WC=32, L=1024
// STRIDE=8 -> 17x17 clipped rectangle mask

typedef __attribute__((ext_vector_type(8))) short bf16x8;
typedef __attribute__((ext_vector_type(4))) float f32x4;

#define SCL 0.18033688f   // 0.125 * log2(e): softmax in exp2 domain, folded into Q

__device__ __forceinline__ unsigned short f2bf(float x) {
  union { float f; unsigned int u; } v; v.f = x;
  unsigned int r = v.u + 0x7FFFu + ((v.u >> 16) & 1u);  // RNE
  return (unsigned short)(r >> 16);
}

__device__ __forceinline__ unsigned int pk2bf(float a, float b) {
  return (unsigned)f2bf(a) | ((unsigned)f2bf(b) << 16);
}

__device__ __forceinline__ unsigned int cvtpk(float a, float b) {
  unsigned int r;
  asm("v_cvt_pk_bf16_f32 %0, %1, %2" : "=v"(r) : "v"(a), "v"(b));
  return r;
}

__device__ __forceinline__ float fexp2(float x) {
#if __has_builtin(__builtin_amdgcn_exp2f)
  return __builtin_amdgcn_exp2f(x);
#else
  return exp2f(x);
#endif
}

// LDS tile swizzle for attn: [row][chunk-of-16B] -> byte offset, XOR bank spread
__device__ __forceinline__ int swzb(int row, int chk) {
  return row * 128 + ((chk * 16) ^ ((row & 7) << 4));
}

// ---- prep: weights -> N-major bf16, tiled transpose (coalesced both sides) ----
__global__ __launch_bounds__(256) void prep_w(const float* __restrict__ Wq, const float* __restrict__ Wk,
                                              const float* __restrict__ Wv, const float* __restrict__ Wo,
                                              unsigned short* __restrict__ Wqt, unsigned short* __restrict__ Wkt,
                                              unsigned short* __restrict__ Wvt, unsigned short* __restrict__ Wot) {
  __shared__ float tile[64][65];
  const int bid = blockIdx.x;           // 256 = 4 weights x 8 x 8 tiles
  const int wsel = bid >> 6, tt = bid & 63;
  const int kt = (tt >> 3) << 6, ntb = (tt & 7) << 6;
  const float* W = (wsel == 0) ? Wq : (wsel == 1) ? Wk : (wsel == 2) ? Wv : Wo;
  unsigned short* Wt = (wsel == 0) ? Wqt : (wsel == 1) ? Wkt : (wsel == 2) ? Wvt : Wot;
  const int t = threadIdx.x;
#pragma unroll
  for (int p = 0; p < 16; ++p) {
    int e = p * 256 + t;
    int row = e >> 6, col = e & 63;
    tile[row][col] = W[(long)(kt + row) * 512 + ntb + col];
  }
  __syncthreads();
#pragma unroll
  for (int p = 0; p < 16; ++p) {
    int e = p * 256 + t;
    int n = e >> 6, k = e & 63;
    Wt[(long)(ntb + n) * 512 + kt + k] = f2bf(tile[k][n]);
  }
}

// ---- prep: inputs -> bf16 once; blocks >= 6144 do per-batch cr counting sort ----
__global__ __launch_bounds__(256) void prep_in(const float* __restrict__ feats,
                                               const int* __restrict__ coords,
                                               const float* __restrict__ pos_emb,
                                               const float* __restrict__ ctx,
                                               const float* __restrict__ ctx_pos,
                                               unsigned short* __restrict__ Aq,
                                               unsigned short* __restrict__ Ac,
                                               int* __restrict__ perm) {
  if (blockIdx.x >= 6144) {
    // counting sort of batch bb's 2048 queries by center-row cr (bins 0..32)
    __shared__ int hist[64];
    __shared__ int base[64];
    const int bb = blockIdx.x - 6144;
    const int t = threadIdx.x;
    if (t < 64) hist[t] = 0;
    __syncthreads();
    int keys[8];
#pragma unroll
    for (int i = 0; i < 8; ++i) {
      int q = bb * 2048 + t * 8 + i;
      int cr = (int)rintf((float)coords[2 * q] * 0.0625f);
      keys[i] = cr;
      atomicAdd(&hist[cr], 1);
    }
    __syncthreads();
    if (t == 0) {
      int s = 0;
      for (int k2 = 0; k2 < 64; ++k2) { base[k2] = s; s += hist[k2]; }
    }
    __syncthreads();
#pragma unroll
    for (int i = 0; i < 8; ++i) {
      int pos = atomicAdd(&base[keys[i]], 1);
      perm[bb * 2048 + pos] = t * 8 + i;
    }
    return;
  }
  int i = blockIdx.x * 256 + threadIdx.x;    // < 1,572,864
  if (i < 1048576) {
    int e = i << 2;
    int q = e >> 9, k = e & 511;
    int pi = ((coords[2 * q] >> 3) << 6) + (coords[2 * q + 1] >> 3);
    float4 a = *(const float4*)(feats + e);
    float4 p = *(const float4*)(pos_emb + ((size_t)pi << 9) + k);
    uint2 o;
    o.x = pk2bf(a.x + p.x, a.y + p.y);
    o.y = pk2bf(a.z + p.z, a.w + p.w);
    *(uint2*)(Aq + e) = o;
  } else {
    int e = (i - 1048576) << 2;
    int r = e >> 9, k = e & 511;
    float4 a = *(const float4*)(ctx + e);
    float4 p = *(const float4*)(ctx_pos + ((size_t)(r & 1023) << 9) + k);
    uint2 o;
    o.x = pk2bf(a.x + p.x, a.y + p.y);
    o.y = pk2bf(a.z + p.z, a.w + p.w);
    *(uint2*)(Ac + e) = o;
  }
}

// ---- fused Q|K|V projections: bf16 A, 128x128 tile, BK=64, prefetch-ahead ----
__global__ __launch_bounds__(256) void gemm_qkv(const unsigned short* __restrict__ Aq,
                                                const unsigned short* __restrict__ Ac,
                                                const unsigned short* __restrict__ Wqt,
                                                const unsigned short* __restrict__ Wkt,
                                                const unsigned short* __restrict__ Wvt,
                                                unsigned short* __restrict__ Qb,
                                                unsigned short* __restrict__ Kb,
                                                unsigned short* __restrict__ Vt) {
  __shared__ unsigned short As[128][72];
  __shared__ unsigned short Bs[128][72];
  const int t = threadIdx.x, l = t & 63, wid = t >> 6;
  const int wr = (wid >> 1) << 6, wc = (wid & 1) << 6;
  const int orig = blockIdx.x;
  const int bx = (orig & 7) * 64 + (orig >> 3);   // chunked XCD swizzle (512 wgs)
  const bool isQ = bx < 256;
  long tm; const unsigned short* Bt; const unsigned short* Ab; bool isV = false; int nt;
  if (isQ) {
    tm = (long)(bx >> 2) * 128;
    nt = bx & 3;
    Bt = Wqt + (long)nt * 65536;
    Ab = Aq;
  } else {
    const int kvx = bx - 256;
    tm = (long)(kvx >> 3) * 128;
    const int y = kvx & 7;
    isV = y >= 4; nt = y & 3;
    Bt = (isV ? Wvt : Wkt) + (long)nt * 65536;
    Ab = Ac;
  }

  f32x4 acc[4][4] = {};
  const int lr = l & 15, lk = (l >> 4) << 3;
  const int srw = t >> 3, sch = (t & 7) << 3;

  int4 rav[4], rbv[4];
  auto LOADAB = [&](int k0) {
#pragma unroll
    for (int p = 0; p < 4; ++p) {
      int row = srw + (p << 5);
      rav[p] = *(const int4*)(Ab + (tm + row) * 512 + k0 + sch);
      rbv[p] = *(const int4*)(Bt + (long)row * 512 + k0 + sch);
    }
  };
  auto WRITEAB = [&]() {
#pragma unroll
    for (int p = 0; p < 4; ++p) {
      int row = srw + (p << 5);
      *(int4*)(&As[row][sch]) = rav[p];
      *(int4*)(&Bs[row][sch]) = rbv[p];
    }
  };

  LOADAB(0);
  WRITEAB();
  __syncthreads();

  for (int s = 0; s < 8; ++s) {
    if (s < 7) LOADAB((s + 1) << 6);     // issue early: completes under MFMA
#pragma unroll
    for (int kk = 0; kk < 2; ++kk) {
      bf16x8 af[4], bfr[4];
#pragma unroll
      for (int i = 0; i < 4; ++i) af[i]  = *(const bf16x8*)(&As[wr + i * 16 + lr][kk * 32 + lk]);
#pragma unroll
      for (int i = 0; i < 4; ++i) bfr[i] = *(const bf16x8*)(&Bs[wc + i * 16 + lr][kk * 32 + lk]);
#pragma unroll
      for (int mi = 0; mi < 4; ++mi)
#pragma unroll
        for (int ni = 0; ni < 4; ++ni)
          acc[mi][ni] = __builtin_amdgcn_mfma_f32_16x16x32_bf16(af[mi], bfr[ni], acc[mi][ni], 0, 0, 0);
    }
    __syncthreads();
    if (s < 7) {
      WRITEAB();
      __syncthreads();
    }
  }

  const int lq = (l >> 4) << 2;
#pragma unroll
  for (int mi = 0; mi < 4; ++mi)
#pragma unroll
    for (int ni = 0; ni < 4; ++ni) {
      int cn = nt * 128 + wc + ni * 16 + lr;
      long r0 = tm + wr + mi * 16 + lq;
      if (isQ) {
#pragma unroll
        for (int r = 0; r < 4; ++r)
          Qb[(r0 + r) * 512 + cn] = f2bf(acc[mi][ni][r] * SCL);
      } else if (!isV) {
#pragma unroll
        for (int r = 0; r < 4; ++r)
          Kb[(r0 + r) * 512 + cn] = f2bf(acc[mi][ni][r]);
      } else {
        int h = cn >> 6, d = cn & 63;
#pragma unroll
        for (int r = 0; r < 4; ++r) {
          long row = r0 + r;
          int b = (int)(row >> 10), j = (int)(row & 1023);
          int jp = (j & ~63) | ((j & 15) << 2) | ((j >> 4) & 3);
          Vt[((long)(b * 8 + h) * 64 + d) * 1024 + jp] = f2bf(acc[mi][ni][r]);
        }
      }
    }
}

// ---- MFMA masked flash attention: 8 waves x 16 sorted q-rows, wave-range skip ----
// 512 blocks (XCD-swizzled): sw&15 = q-slot-tile of 128, sw>>4 = b*8+h.
__global__ __launch_bounds__(512, 4) void attn_mfma(const unsigned short* __restrict__ Qb,
                                                    const unsigned short* __restrict__ Kb,
                                                    const unsigned short* __restrict__ Vt,
                                                    const int* __restrict__ coords,
                                                    const int* __restrict__ perm,
                                                    unsigned short* __restrict__ Abf) {
  __shared__ char Kl[2][8192];                 // 64 keys x 64 d (swizzled)
  __shared__ char Vl[2][8192];                 // 64 d x 64 keys' (swizzled, interleaved)
  __shared__ char Ol[2048];                    // 16 x 64: row0 = ones (row-sum column)
  __shared__ unsigned short Plds[8][16][72];   // per-wave P (col' = 4*lc + kf)
  __shared__ int permL[128];
  __shared__ int rng[2];
  const int t = threadIdx.x, w = t >> 6, l = t & 63;
  const int g = l >> 4, lc = l & 15;
  const int orig = blockIdx.x;
  const int sw = (orig & 7) * 64 + (orig >> 3);    // chunked XCD swizzle (512 wgs)
  const int qx = sw & 15, bh = sw >> 4;
  const int b = bh >> 3, h = bh & 7;

  if (t < 128) permL[t] = perm[b * 2048 + qx * 128 + t];
  if (t == 0) { rng[0] = 63; rng[1] = 0; }
  __syncthreads();

  // rect bitmasks for the 4 sorted query-rows this lane reduces (slots w*16+g*4+r)
  int rm[4], cm[4];
  int lrmin = 63, lrmax = 0;
#pragma unroll
  for (int r = 0; r < 4; ++r) {
    long qq = (long)b * 2048 + permL[w * 16 + g * 4 + r];
    int cr = (int)rintf((float)coords[2 * qq] * 0.0625f);      // round-half-even = jnp.round
    int cc = (int)rintf((float)coords[2 * qq + 1] * 0.0625f);
    int rlo = max(0, cr - 8), rhi = min(31, cr + 8);
    int clo = max(0, cc - 8), chi = min(31, cc + 8);
    rm[r] = (int)((((unsigned)1 << (rhi - rlo + 1)) - 1) << rlo);
    cm[r] = (int)((((unsigned)1 << (chi - clo + 1)) - 1) << clo);
    lrmin = min(lrmin, rlo); lrmax = max(lrmax, rhi);
  }
#pragma unroll
  for (int off = 32; off > 0; off >>= 1) {
    lrmin = min(lrmin, __shfl_xor(lrmin, off));
    lrmax = max(lrmax, __shfl_xor(lrmax, off));
  }
  const int wt0 = lrmin >> 1, wt1 = lrmax >> 1;    // this wave's tile range
  if (l == 0) { atomicMin(&rng[0], lrmin); atomicMax(&rng[1], lrmax); }

  bf16x8 qfr[2];
  {
    long qrow = (long)b * 2048 + permL[w * 16 + lc];
#pragma unroll
    for (int dc = 0; dc < 2; ++dc)
      qfr[dc] = *(const bf16x8*)(Qb + qrow * 512 + h * 64 + dc * 32 + g * 8);
  }

  // staging: 512 threads cover 64 rows x 8 chunks of 16B, one K + one V each
  const int srow = t >> 3, schk = t & 7;
  const unsigned short* Kg = Kb + ((long)b * 1024) * 512 + h * 64;
  const unsigned short* Vg = Vt + ((long)bh * 64) * 1024;

  if (t < 128) {
    int r = t >> 3, c = t & 7;
    unsigned short vv = (r == 0) ? (unsigned short)0x3F80 : (unsigned short)0;
    unsigned short tmp[8] = {vv, vv, vv, vv, vv, vv, vv, vv};
    *(int4*)(Ol + swzb(r, c)) = *(int4*)tmp;
  }
  __syncthreads();
  const int t0 = rng[0] >> 1, t1 = rng[1] >> 1;   // inclusive 64-key tile range
  {
    const int kb0 = t0 * 64;
    int4 sk = *(const int4*)(Kg + (long)(kb0 + srow) * 512 + schk * 8);
    int4 sv_ = *(const int4*)(Vg + (long)srow * 1024 + kb0 + schk * 8);
    *(int4*)(Kl[0] + swzb(srow, schk)) = sk;
    *(int4*)(Vl[0] + swzb(srow, schk)) = sv_;
  }
  __syncthreads();

  f32x4 po[5] = {};   // df=4 is the ones-column (row-sum at col 0)

  for (int kt = t0; kt <= t1; ++kt) {
    const int cur = (kt - t0) & 1;
    const int kb = kt * 64;
    int4 nk = {}, nv = {};
    if (kt < t1) {
      const int kbn = kb + 64;
      nk = *(const int4*)(Kg + (long)(kbn + srow) * 512 + schk * 8);
      nv = *(const int4*)(Vg + (long)srow * 1024 + kbn + schk * 8);
    }

    if (kt >= wt0 && kt <= wt1) {          // wave-uniform skip outside own range
      bf16x8 kfr[4][2];
#pragma unroll
      for (int kf = 0; kf < 4; ++kf)
#pragma unroll
        for (int dc = 0; dc < 2; ++dc)
          kfr[kf][dc] = *(const bf16x8*)(Kl[cur] + swzb(kf * 16 + lc, dc * 4 + g));

      // S = (Q*SCL) K^T
      f32x4 sv[4];
#pragma unroll
      for (int kf = 0; kf < 4; ++kf) {
        f32x4 a = {};
        a = __builtin_amdgcn_mfma_f32_16x16x32_bf16(qfr[0], kfr[kf][0], a, 0, 0, 0);
        a = __builtin_amdgcn_mfma_f32_16x16x32_bf16(qfr[1], kfr[kf][1], a, 0, 0, 0);
        sv[kf] = a;
      }

      // mask: row-bit constant per (tile,kf) -> precompute col-mask, select after exp2
      const int jrb = kb >> 5;
      int cmk[4][4];
#pragma unroll
      for (int kf = 0; kf < 4; ++kf) {
        int jr = jrb + (kf >> 1);
#pragma unroll
        for (int r = 0; r < 4; ++r)
          cmk[kf][r] = ((rm[r] >> jr) & 1) ? cm[r] : 0;
      }
#pragma unroll
      for (int kf = 0; kf < 4; ++kf) {
        int jc = ((kf & 1) << 4) + lc;
#pragma unroll
        for (int r = 0; r < 4; ++r) {
          float p = fexp2(sv[kf][r]);
          sv[kf][r] = ((cmk[kf][r] >> jc) & 1) ? p : 0.0f;
        }
      }

      // V^T fragments; df=4 from ones region
      bf16x8 vfr[5][2];
#pragma unroll
      for (int df = 0; df < 4; ++df)
#pragma unroll
        for (int kc = 0; kc < 2; ++kc)
          vfr[df][kc] = *(const bf16x8*)(Vl[cur] + swzb(df * 16 + lc, kc * 4 + g));
#pragma unroll
      for (int kc = 0; kc < 2; ++kc)
        vfr[4][kc] = *(const bf16x8*)(Ol + swzb(lc, kc * 4 + g));

      // P pack via v_cvt_pk_bf16_f32 -> LDS b64 at col' = 4*lc (+kf), wave-private
#pragma unroll
      for (int r = 0; r < 4; ++r) {
        uint2 pk;
        pk.x = cvtpk(sv[0][r], sv[1][r]);
        pk.y = cvtpk(sv[2][r], sv[3][r]);
        *(uint2*)(&Plds[w][g * 4 + r][4 * lc]) = pk;
      }

      bf16x8 pa0 = *(const bf16x8*)(&Plds[w][lc][g * 8]);
      bf16x8 pa1 = *(const bf16x8*)(&Plds[w][lc][32 + g * 8]);
      __builtin_amdgcn_s_setprio(1);
#pragma unroll
      for (int df = 0; df < 5; ++df) {
        po[df] = __builtin_amdgcn_mfma_f32_16x16x32_bf16(pa0, vfr[df][0], po[df], 0, 0, 0);
        po[df] = __builtin_amdgcn_mfma_f32_16x16x32_bf16(pa1, vfr[df][1], po[df], 0, 0, 0);
      }
      __builtin_amdgcn_s_setprio(0);
    }

    if (kt < t1) {
      const int nxt = cur ^ 1;
      *(int4*)(Kl[nxt] + swzb(srow, schk)) = nk;
      *(int4*)(Vl[nxt] + swzb(srow, schk)) = nv;
    }
    __syncthreads();
  }

  // epilogue: l = ones-column (col 0 of group), normalize, write bf16 (scattered)
#pragma unroll
  for (int r = 0; r < 4; ++r) {
    float lsum = __shfl(po[4][r], l & 48);
    float inv = 1.0f / lsum;
    long qr = (long)b * 2048 + permL[w * 16 + g * 4 + r];
#pragma unroll
    for (int df = 0; df < 4; ++df)
      Abf[qr * 512 + h * 64 + df * 16 + lc] = f2bf(po[df][r] * inv);
  }
}

// ---- output projection: 64x128 tile, BK=64, prefetch-ahead, XCD-swizzled ----
__global__ __launch_bounds__(256) void gemm_o(const unsigned short* __restrict__ A,
                                              const unsigned short* __restrict__ Bt,
                                              float* __restrict__ C,
                                              const float* __restrict__ bias) {
  __shared__ unsigned short As[64][72];
  __shared__ unsigned short Bs[128][72];
  const int t = threadIdx.x, l = t & 63, wid = t >> 6;
  const int wr = (wid >> 1) << 5;
  const int wc = (wid & 1) << 6;
  const int orig = blockIdx.x;
  const int bx = (orig & 7) * 64 + (orig >> 3);    // chunked XCD swizzle (512 wgs)
  const long tm = (long)(bx >> 2) * 64;
  const long tn = (long)(bx & 3) * 128;

  f32x4 acc[2][4] = {};
  const int lr = l & 15, lk = (l >> 4) << 3;

  int4 rAv[2], rBv[4];
  auto LOADAB = [&](int k0) {
#pragma unroll
    for (int p = 0; p < 2; ++p) {
      int e = p * 256 + t;
      int row = e >> 3, ch = (e & 7) << 3;
      rAv[p] = *(const int4*)(A + (tm + row) * 512 + k0 + ch);
    }
#pragma unroll
    for (int p = 0; p < 4; ++p) {
      int e = p * 256 + t;
      int row = e >> 3, ch = (e & 7) << 3;
      rBv[p] = *(const int4*)(Bt + (tn + row) * 512 + k0 + ch);
    }
  };
  auto WRITEAB = [&]() {
#pragma unroll
    for (int p = 0; p < 2; ++p) {
      int e = p * 256 + t;
      int row = e >> 3, ch = (e & 7) << 3;
      *(int4*)(&As[row][ch]) = rAv[p];
    }
#pragma unroll
    for (int p = 0; p < 4; ++p) {
      int e = p * 256 + t;
      int row = e >> 3, ch = (e & 7) << 3;
      *(int4*)(&Bs[row][ch]) = rBv[p];
    }
  };

  LOADAB(0);
  WRITEAB();
  __syncthreads();

  for (int s = 0; s < 8; ++s) {
    if (s < 7) LOADAB((s + 1) << 6);     // issue early: completes under MFMA
#pragma unroll
    for (int kk = 0; kk < 2; ++kk) {
      bf16x8 af[2], bfr[4];
#pragma unroll
      for (int i = 0; i < 2; ++i) af[i]  = *(const bf16x8*)(&As[wr + i * 16 + lr][kk * 32 + lk]);
#pragma unroll
      for (int i = 0; i < 4; ++i) bfr[i] = *(const bf16x8*)(&Bs[wc + i * 16 + lr][kk * 32 + lk]);
#pragma unroll
      for (int mi = 0; mi < 2; ++mi)
#pragma unroll
        for (int ni = 0; ni < 4; ++ni)
          acc[mi][ni] = __builtin_amdgcn_mfma_f32_16x16x32_bf16(af[mi], bfr[ni], acc[mi][ni], 0, 0, 0);
    }
    __syncthreads();
    if (s < 7) {
      WRITEAB();
      __syncthreads();
    }
  }

  const int lq = (l >> 4) << 2;
#pragma unroll
  for (int mi = 0; mi < 2; ++mi)
#pragma unroll
    for (int ni = 0; ni < 4; ++ni) {
      long col = tn + wc + ni * 16 + lr;
      float bv = bias[col];
      long r0 = tm + wr + mi * 16 + lq;
#pragma unroll
      for (int r = 0; r < 4; ++r)
        C[(r0 + r) * 512 + col] = acc[mi][ni][r] + bv;
    }
}

extern "C" void kernel_launch(void* const* d_in, const int* in_sizes, int n_in,
                              void* d_out, int out_size, void* d_ws, size_t ws_size,
                              hipStream_t stream) {
  (void)in_sizes; (void)n_in; (void)out_size; (void)ws_size;
  const float* feats   = (const float*)d_in[0];
  const int*   coords  = (const int*)d_in[1];
  const float* ctx     = (const float*)d_in[2];
  const float* Wq      = (const float*)d_in[3];
  const float* Wk      = (const float*)d_in[4];
  const float* Wv      = (const float*)d_in[5];
  const float* Wo      = (const float*)d_in[6];
  const float* bo      = (const float*)d_in[7];
  const float* pos_emb = (const float*)d_in[8];
  const float* ctx_pos = (const float*)d_in[9];
  float* out = (float*)d_out;
  char* ws = (char*)d_ws;

  unsigned short* Wqt = (unsigned short*)(ws);               //   524,288
  unsigned short* Wkt = (unsigned short*)(ws + 524288);
  unsigned short* Wvt = (unsigned short*)(ws + 1048576);
  unsigned short* Wot = (unsigned short*)(ws + 1572864);
  unsigned short* Aq  = (unsigned short*)(ws + 2097152);     // 8,388,608
  unsigned short* Ac  = (unsigned short*)(ws + 10485760);    // 4,194,304
  unsigned short* Qb  = (unsigned short*)(ws + 14680064);    // 8,388,608
  unsigned short* Kb  = (unsigned short*)(ws + 23068672);    // 4,194,304
  unsigned short* Vt  = (unsigned short*)(ws + 27262976);    // 4,194,304
  unsigned short* Abf = (unsigned short*)(ws + 31457280);    // 8,388,608
  int*            prm = (int*)(ws + 39845888);               //    32,768 (end 39,878,656)

  prep_w  <<<256, 256, 0, stream>>>(Wq, Wk, Wv, Wo, Wqt, Wkt, Wvt, Wot);
  prep_in <<<6148, 256, 0, stream>>>(feats, coords, pos_emb, ctx, ctx_pos, Aq, Ac, prm);
  gemm_qkv<<<512, 256, 0, stream>>>(Aq, Ac, Wqt, Wkt, Wvt, Qb, Kb, Vt);
  attn_mfma<<<512, 512, 0, stream>>>(Qb, Kb, Vt, coords, prm, Abf);
  gemm_o  <<<512, 256, 0, stream>>>(Abf, Wot, out, bo);
}

// Round 14
// 80.686 us; speedup vs baseline: 1.5621x; 1.5621x over previous
//
#include <hip/hip_runtime.h>

// B=4, P=2048, N=8192, QD=CD=INNER=512, HEADS=8, DH=64, HC=WC=32, L=1024
// STRIDE=8 -> 17x17 clipped rectangle mask

typedef __attribute__((ext_vector_type(8))) short bf16x8;
typedef __attribute__((ext_vector_type(4))) float f32x4;

#define SCL 0.18033688f   // 0.125 * log2(e): softmax in exp2 domain, folded into Q

__device__ __forceinline__ unsigned short f2bf(float x) {
  union { float f; unsigned int u; } v; v.f = x;
  unsigned int r = v.u + 0x7FFFu + ((v.u >> 16) & 1u);  // RNE
  return (unsigned short)(r >> 16);
}

__device__ __forceinline__ unsigned int pk2bf(float a, float b) {
  return (unsigned)f2bf(a) | ((unsigned)f2bf(b) << 16);
}

__device__ __forceinline__ unsigned int cvtpk(float a, float b) {
  unsigned int r;
  asm("v_cvt_pk_bf16_f32 %0, %1, %2" : "=v"(r) : "v"(a), "v"(b));
  return r;
}

__device__ __forceinline__ float fexp2(float x) {
#if __has_builtin(__builtin_amdgcn_exp2f)
  return __builtin_amdgcn_exp2f(x);
#else
  return exp2f(x);
#endif
}

// async global->LDS, 16B per lane; LDS dest = wave-uniform base + lane*16
__device__ __forceinline__ void gload16(const unsigned short* g, char* l) {
  __builtin_amdgcn_global_load_lds(
      (const __attribute__((address_space(1))) unsigned int*)g,
      (__attribute__((address_space(3))) unsigned int*)l, 16, 0, 0);
}

// LDS tile swizzle: [row][16B-chunk] -> byte offset (XOR involution, both sides)
__device__ __forceinline__ int swzb(int row, int chk) {
  return row * 128 + ((chk * 16) ^ ((row & 7) << 4));
}

// ---- prep: weights -> N-major bf16, tiled transpose (coalesced both sides) ----
__global__ __launch_bounds__(256) void prep_w(const float* __restrict__ Wq, const float* __restrict__ Wk,
                                              const float* __restrict__ Wv, const float* __restrict__ Wo,
                                              unsigned short* __restrict__ Wqt, unsigned short* __restrict__ Wkt,
                                              unsigned short* __restrict__ Wvt, unsigned short* __restrict__ Wot) {
  __shared__ float tile[64][65];
  const int bid = blockIdx.x;           // 256 = 4 weights x 8 x 8 tiles
  const int wsel = bid >> 6, tt = bid & 63;
  const int kt = (tt >> 3) << 6, ntb = (tt & 7) << 6;
  const float* W = (wsel == 0) ? Wq : (wsel == 1) ? Wk : (wsel == 2) ? Wv : Wo;
  unsigned short* Wt = (wsel == 0) ? Wqt : (wsel == 1) ? Wkt : (wsel == 2) ? Wvt : Wot;
  const int t = threadIdx.x;
#pragma unroll
  for (int p = 0; p < 16; ++p) {
    int e = p * 256 + t;
    int row = e >> 6, col = e & 63;
    tile[row][col] = W[(long)(kt + row) * 512 + ntb + col];
  }
  __syncthreads();
#pragma unroll
  for (int p = 0; p < 16; ++p) {
    int e = p * 256 + t;
    int n = e >> 6, k = e & 63;
    Wt[(long)(ntb + n) * 512 + kt + k] = f2bf(tile[k][n]);
  }
}

// ---- prep: inputs -> bf16 once; blocks >= 6144 do per-batch cr counting sort ----
__global__ __launch_bounds__(256) void prep_in(const float* __restrict__ feats,
                                               const int* __restrict__ coords,
                                               const float* __restrict__ pos_emb,
                                               const float* __restrict__ ctx,
                                               const float* __restrict__ ctx_pos,
                                               unsigned short* __restrict__ Aq,
                                               unsigned short* __restrict__ Ac,
                                               int* __restrict__ perm) {
  if (blockIdx.x >= 6144) {
    __shared__ int hist[64];
    __shared__ int base[64];
    const int bb = blockIdx.x - 6144;
    const int t = threadIdx.x;
    if (t < 64) hist[t] = 0;
    __syncthreads();
    int keys[8];
#pragma unroll
    for (int i = 0; i < 8; ++i) {
      int q = bb * 2048 + t * 8 + i;
      int cr = (int)rintf((float)coords[2 * q] * 0.0625f);
      keys[i] = cr;
      atomicAdd(&hist[cr], 1);
    }
    __syncthreads();
    if (t == 0) {
      int s = 0;
      for (int k2 = 0; k2 < 64; ++k2) { base[k2] = s; s += hist[k2]; }
    }
    __syncthreads();
#pragma unroll
    for (int i = 0; i < 8; ++i) {
      int pos = atomicAdd(&base[keys[i]], 1);
      perm[bb * 2048 + pos] = t * 8 + i;
    }
    return;
  }
  int i = blockIdx.x * 256 + threadIdx.x;    // < 1,572,864
  if (i < 1048576) {
    int e = i << 2;
    int q = e >> 9, k = e & 511;
    int pi = ((coords[2 * q] >> 3) << 6) + (coords[2 * q + 1] >> 3);
    float4 a = *(const float4*)(feats + e);
    float4 p = *(const float4*)(pos_emb + ((size_t)pi << 9) + k);
    uint2 o;
    o.x = pk2bf(a.x + p.x, a.y + p.y);
    o.y = pk2bf(a.z + p.z, a.w + p.w);
    *(uint2*)(Aq + e) = o;
  } else {
    int e = (i - 1048576) << 2;
    int r = e >> 9, k = e & 511;
    float4 a = *(const float4*)(ctx + e);
    float4 p = *(const float4*)(ctx_pos + ((size_t)(r & 1023) << 9) + k);
    uint2 o;
    o.x = pk2bf(a.x + p.x, a.y + p.y);
    o.y = pk2bf(a.z + p.z, a.w + p.w);
    *(uint2*)(Ac + e) = o;
  }
}

// ---- fused Q|K|V projections: 128x128 tile, BK=64, global_load_lds dbuf ----
// bx<256: Q (pre-scaled by SCL). bx>=256: K|V (V transposed d-major, keys
// interleaved within 64-tiles: pos = (j&~63) | ((j&15)<<2) | ((j>>4)&3)).
__global__ __launch_bounds__(256) void gemm_qkv(const unsigned short* __restrict__ Aq,
                                                const unsigned short* __restrict__ Ac,
                                                const unsigned short* __restrict__ Wqt,
                                                const unsigned short* __restrict__ Wkt,
                                                const unsigned short* __restrict__ Wvt,
                                                unsigned short* __restrict__ Qb,
                                                unsigned short* __restrict__ Kb,
                                                unsigned short* __restrict__ Vt) {
  __shared__ char Asf[2][16384];   // 128 rows x 64 k, linear (content swizzled)
  __shared__ char Bsf[2][16384];
  const int t = threadIdx.x, l = t & 63, wv = t >> 6;
  const int wr = (wv >> 1) << 6, wc = (wv & 1) << 6;
  const int orig = blockIdx.x;
  const int bx = (orig & 7) * 64 + (orig >> 3);   // chunked XCD swizzle (512 wgs)
  const bool isQ = bx < 256;
  long tm; const unsigned short* Bt; const unsigned short* Ab; bool isV = false; int nt;
  if (isQ) {
    tm = (long)(bx >> 2) * 128;
    nt = bx & 3;
    Bt = Wqt + (long)nt * 65536;
    Ab = Aq;
  } else {
    const int kvx = bx - 256;
    tm = (long)(kvx >> 3) * 128;
    const int y = kvx & 7;
    isV = y >= 4; nt = y & 3;
    Bt = (isV ? Wvt : Wkt) + (long)nt * 65536;
    Ab = Ac;
  }

  // staging: per wave 4 x 1KB chunks for A and B; source chunk XOR-preswizzled
  const int rr = l >> 3, chs = (l & 7) ^ rr;      // lane's row-in-8, source chunk
  auto STAGE = [&](int buf, int k0) {
#pragma unroll
    for (int i = 0; i < 4; ++i) {
      int c = (wv << 2) + i;
      int row = (c << 3) + rr;
      gload16(Ab + (tm + row) * 512 + k0 + chs * 8, Asf[buf] + (c << 10));
      gload16(Bt + (long)row * 512 + k0 + chs * 8, Bsf[buf] + (c << 10));
    }
  };

  STAGE(0, 0);
  __syncthreads();                                 // drains vmcnt

  f32x4 acc[4][4] = {};
  const int lr = l & 15, g = l >> 4;

  for (int s = 0; s < 8; ++s) {
    const int cur = s & 1;
    if (s < 7) STAGE(cur ^ 1, (s + 1) << 6);       // async, flies under MFMA
#pragma unroll
    for (int kk = 0; kk < 2; ++kk) {
      const int chd = (kk << 2) + g;
      bf16x8 af[4], bfr[4];
#pragma unroll
      for (int i = 0; i < 4; ++i) {
        int ra = wr + i * 16 + lr;
        int rb = wc + i * 16 + lr;
        af[i]  = *(const bf16x8*)(Asf[cur] + swzb(ra, chd));
        bfr[i] = *(const bf16x8*)(Bsf[cur] + swzb(rb, chd));
      }
#pragma unroll
      for (int mi = 0; mi < 4; ++mi)
#pragma unroll
        for (int ni = 0; ni < 4; ++ni)
          acc[mi][ni] = __builtin_amdgcn_mfma_f32_16x16x32_bf16(af[mi], bfr[ni], acc[mi][ni], 0, 0, 0);
    }
    __syncthreads();                               // also drains prefetch vmcnt
  }

  const int lq = g << 2;
#pragma unroll
  for (int mi = 0; mi < 4; ++mi)
#pragma unroll
    for (int ni = 0; ni < 4; ++ni) {
      int cn = nt * 128 + wc + ni * 16 + lr;
      long r0 = tm + wr + mi * 16 + lq;
      if (isQ) {
#pragma unroll
        for (int r = 0; r < 4; ++r)
          Qb[(r0 + r) * 512 + cn] = f2bf(acc[mi][ni][r] * SCL);
      } else if (!isV) {
#pragma unroll
        for (int r = 0; r < 4; ++r)
          Kb[(r0 + r) * 512 + cn] = f2bf(acc[mi][ni][r]);
      } else {
        int h = cn >> 6, d = cn & 63;
#pragma unroll
        for (int r = 0; r < 4; ++r) {
          long row = r0 + r;
          int b = (int)(row >> 10), j = (int)(row & 1023);
          int jp = (j & ~63) | ((j & 15) << 2) | ((j >> 4) & 3);
          Vt[((long)(b * 8 + h) * 64 + d) * 1024 + jp] = f2bf(acc[mi][ni][r]);
        }
      }
    }
}

// ---- MFMA masked flash attention: 8 waves x 16 sorted q-rows, wave-range skip ----
__global__ __launch_bounds__(512, 4) void attn_mfma(const unsigned short* __restrict__ Qb,
                                                    const unsigned short* __restrict__ Kb,
                                                    const unsigned short* __restrict__ Vt,
                                                    const int* __restrict__ coords,
                                                    const int* __restrict__ perm,
                                                    unsigned short* __restrict__ Abf) {
  __shared__ char Kl[2][8192];                 // 64 keys x 64 d (swizzled)
  __shared__ char Vl[2][8192];                 // 64 d x 64 keys' (swizzled, interleaved)
  __shared__ char Ol[2048];                    // 16 x 64: row0 = ones (row-sum column)
  __shared__ unsigned short Plds[8][16][72];   // per-wave P (col' = 4*lc + kf)
  __shared__ int permL[128];
  __shared__ int rng[2];
  const int t = threadIdx.x, w = t >> 6, l = t & 63;
  const int g = l >> 4, lc = l & 15;
  const int orig = blockIdx.x;
  const int sw = (orig & 7) * 64 + (orig >> 3);    // chunked XCD swizzle (512 wgs)
  const int qx = sw & 15, bh = sw >> 4;
  const int b = bh >> 3, h = bh & 7;

  if (t < 128) permL[t] = perm[b * 2048 + qx * 128 + t];
  if (t == 0) { rng[0] = 63; rng[1] = 0; }
  __syncthreads();

  int rm[4], cm[4];
  int lrmin = 63, lrmax = 0;
#pragma unroll
  for (int r = 0; r < 4; ++r) {
    long qq = (long)b * 2048 + permL[w * 16 + g * 4 + r];
    int cr = (int)rintf((float)coords[2 * qq] * 0.0625f);      // round-half-even = jnp.round
    int cc = (int)rintf((float)coords[2 * qq + 1] * 0.0625f);
    int rlo = max(0, cr - 8), rhi = min(31, cr + 8);
    int clo = max(0, cc - 8), chi = min(31, cc + 8);
    rm[r] = (int)((((unsigned)1 << (rhi - rlo + 1)) - 1) << rlo);
    cm[r] = (int)((((unsigned)1 << (chi - clo + 1)) - 1) << clo);
    lrmin = min(lrmin, rlo); lrmax = max(lrmax, rhi);
  }
#pragma unroll
  for (int off = 32; off > 0; off >>= 1) {
    lrmin = min(lrmin, __shfl_xor(lrmin, off));
    lrmax = max(lrmax, __shfl_xor(lrmax, off));
  }
  const int wt0 = lrmin >> 1, wt1 = lrmax >> 1;
  if (l == 0) { atomicMin(&rng[0], lrmin); atomicMax(&rng[1], lrmax); }

  bf16x8 qfr[2];
  {
    long qrow = (long)b * 2048 + permL[w * 16 + lc];
#pragma unroll
    for (int dc = 0; dc < 2; ++dc)
      qfr[dc] = *(const bf16x8*)(Qb + qrow * 512 + h * 64 + dc * 32 + g * 8);
  }

  const int srow = t >> 3, schk = t & 7;
  const unsigned short* Kg = Kb + ((long)b * 1024) * 512 + h * 64;
  const unsigned short* Vg = Vt + ((long)bh * 64) * 1024;

  if (t < 128) {
    int r = t >> 3, c = t & 7;
    unsigned short vv = (r == 0) ? (unsigned short)0x3F80 : (unsigned short)0;
    unsigned short tmp[8] = {vv, vv, vv, vv, vv, vv, vv, vv};
    *(int4*)(Ol + swzb(r, c)) = *(int4*)tmp;
  }
  __syncthreads();
  const int t0 = rng[0] >> 1, t1 = rng[1] >> 1;
  {
    const int kb0 = t0 * 64;
    int4 sk = *(const int4*)(Kg + (long)(kb0 + srow) * 512 + schk * 8);
    int4 sv_ = *(const int4*)(Vg + (long)srow * 1024 + kb0 + schk * 8);
    *(int4*)(Kl[0] + swzb(srow, schk)) = sk;
    *(int4*)(Vl[0] + swzb(srow, schk)) = sv_;
  }
  __syncthreads();

  f32x4 po[5] = {};

  for (int kt = t0; kt <= t1; ++kt) {
    const int cur = (kt - t0) & 1;
    const int kb = kt * 64;
    int4 nk = {}, nv = {};
    if (kt < t1) {
      const int kbn = kb + 64;
      nk = *(const int4*)(Kg + (long)(kbn + srow) * 512 + schk * 8);
      nv = *(const int4*)(Vg + (long)srow * 1024 + kbn + schk * 8);
    }

    if (kt >= wt0 && kt <= wt1) {          // wave-uniform skip outside own range
      bf16x8 kfr[4][2];
#pragma unroll
      for (int kf = 0; kf < 4; ++kf)
#pragma unroll
        for (int dc = 0; dc < 2; ++dc)
          kfr[kf][dc] = *(const bf16x8*)(Kl[cur] + swzb(kf * 16 + lc, dc * 4 + g));

      f32x4 sv[4];
#pragma unroll
      for (int kf = 0; kf < 4; ++kf) {
        f32x4 a = {};
        a = __builtin_amdgcn_mfma_f32_16x16x32_bf16(qfr[0], kfr[kf][0], a, 0, 0, 0);
        a = __builtin_amdgcn_mfma_f32_16x16x32_bf16(qfr[1], kfr[kf][1], a, 0, 0, 0);
        sv[kf] = a;
      }

      const int jrb = kb >> 5;
      int cmk[4][4];
#pragma unroll
      for (int kf = 0; kf < 4; ++kf) {
        int jr = jrb + (kf >> 1);
#pragma unroll
        for (int r = 0; r < 4; ++r)
          cmk[kf][r] = ((rm[r] >> jr) & 1) ? cm[r] : 0;
      }
#pragma unroll
      for (int kf = 0; kf < 4; ++kf) {
        int jc = ((kf & 1) << 4) + lc;
#pragma unroll
        for (int r = 0; r < 4; ++r) {
          float p = fexp2(sv[kf][r]);
          sv[kf][r] = ((cmk[kf][r] >> jc) & 1) ? p : 0.0f;
        }
      }

      bf16x8 vfr[5][2];
#pragma unroll
      for (int df = 0; df < 4; ++df)
#pragma unroll
        for (int kc = 0; kc < 2; ++kc)
          vfr[df][kc] = *(const bf16x8*)(Vl[cur] + swzb(df * 16 + lc, kc * 4 + g));
#pragma unroll
      for (int kc = 0; kc < 2; ++kc)
        vfr[4][kc] = *(const bf16x8*)(Ol + swzb(lc, kc * 4 + g));

#pragma unroll
      for (int r = 0; r < 4; ++r) {
        uint2 pk;
        pk.x = cvtpk(sv[0][r], sv[1][r]);
        pk.y = cvtpk(sv[2][r], sv[3][r]);
        *(uint2*)(&Plds[w][g * 4 + r][4 * lc]) = pk;
      }

      bf16x8 pa0 = *(const bf16x8*)(&Plds[w][lc][g * 8]);
      bf16x8 pa1 = *(const bf16x8*)(&Plds[w][lc][32 + g * 8]);
      __builtin_amdgcn_s_setprio(1);
#pragma unroll
      for (int df = 0; df < 5; ++df) {
        po[df] = __builtin_amdgcn_mfma_f32_16x16x32_bf16(pa0, vfr[df][0], po[df], 0, 0, 0);
        po[df] = __builtin_amdgcn_mfma_f32_16x16x32_bf16(pa1, vfr[df][1], po[df], 0, 0, 0);
      }
      __builtin_amdgcn_s_setprio(0);
    }

    if (kt < t1) {
      const int nxt = cur ^ 1;
      *(int4*)(Kl[nxt] + swzb(srow, schk)) = nk;
      *(int4*)(Vl[nxt] + swzb(srow, schk)) = nv;
    }
    __syncthreads();
  }

#pragma unroll
  for (int r = 0; r < 4; ++r) {
    float lsum = __shfl(po[4][r], l & 48);
    float inv = 1.0f / lsum;
    long qr = (long)b * 2048 + permL[w * 16 + g * 4 + r];
#pragma unroll
    for (int df = 0; df < 4; ++df)
      Abf[qr * 512 + h * 64 + df * 16 + lc] = f2bf(po[df][r] * inv);
  }
}

// ---- output projection: 64x128 tile, BK=64, global_load_lds dbuf ----
__global__ __launch_bounds__(256) void gemm_o(const unsigned short* __restrict__ A,
                                              const unsigned short* __restrict__ Bt,
                                              float* __restrict__ C,
                                              const float* __restrict__ bias) {
  __shared__ char Asf[2][8192];    // 64 rows x 64 k, linear (content swizzled)
  __shared__ char Bsf[2][16384];   // 128 rows x 64 k
  const int t = threadIdx.x, l = t & 63, wv = t >> 6;
  const int wr = (wv >> 1) << 5;
  const int wc = (wv & 1) << 6;
  const int orig = blockIdx.x;
  const int bx = (orig & 7) * 64 + (orig >> 3);    // chunked XCD swizzle (512 wgs)
  const long tm = (long)(bx >> 2) * 64;
  const long tn = (long)(bx & 3) * 128;

  const int rr = l >> 3, chs = (l & 7) ^ rr;
  auto STAGE = [&](int buf, int k0) {
#pragma unroll
    for (int i = 0; i < 2; ++i) {
      int c = (wv << 1) + i;
      int row = (c << 3) + rr;
      gload16(A + (tm + row) * 512 + k0 + chs * 8, Asf[buf] + (c << 10));
    }
#pragma unroll
    for (int i = 0; i < 4; ++i) {
      int c = (wv << 2) + i;
      int row = (c << 3) + rr;
      gload16(Bt + (tn + row) * 512 + k0 + chs * 8, Bsf[buf] + (c << 10));
    }
  };

  STAGE(0, 0);
  __syncthreads();

  f32x4 acc[2][4] = {};
  const int lr = l & 15, g = l >> 4;

  for (int s = 0; s < 8; ++s) {
    const int cur = s & 1;
    if (s < 7) STAGE(cur ^ 1, (s + 1) << 6);
#pragma unroll
    for (int kk = 0; kk < 2; ++kk) {
      const int chd = (kk << 2) + g;
      bf16x8 af[2], bfr[4];
#pragma unroll
      for (int i = 0; i < 2; ++i)
        af[i] = *(const bf16x8*)(Asf[cur] + swzb(wr + i * 16 + lr, chd));
#pragma unroll
      for (int i = 0; i < 4; ++i)
        bfr[i] = *(const bf16x8*)(Bsf[cur] + swzb(wc + i * 16 + lr, chd));
#pragma unroll
      for (int mi = 0; mi < 2; ++mi)
#pragma unroll
        for (int ni = 0; ni < 4; ++ni)
          acc[mi][ni] = __builtin_amdgcn_mfma_f32_16x16x32_bf16(af[mi], bfr[ni], acc[mi][ni], 0, 0, 0);
    }
    __syncthreads();
  }

  const int lq = g << 2;
#pragma unroll
  for (int mi = 0; mi < 2; ++mi)
#pragma unroll
    for (int ni = 0; ni < 4; ++ni) {
      long col = tn + wc + ni * 16 + lr;
      float bv = bias[col];
      long r0 = tm + wr + mi * 16 + lq;
#pragma unroll
      for (int r = 0; r < 4; ++r)
        C[(r0 + r) * 512 + col] = acc[mi][ni][r] + bv;
    }
}

extern "C" void kernel_launch(void* const* d_in, const int* in_sizes, int n_in,
                              void* d_out, int out_size, void* d_ws, size_t ws_size,
                              hipStream_t stream) {
  (void)in_sizes; (void)n_in; (void)out_size; (void)ws_size;
  const float* feats   = (const float*)d_in[0];
  const int*   coords  = (const int*)d_in[1];
  const float* ctx     = (const float*)d_in[2];
  const float* Wq      = (const float*)d_in[3];
  const float* Wk      = (const float*)d_in[4];
  const float* Wv      = (const float*)d_in[5];
  const float* Wo      = (const float*)d_in[6];
  const float* bo      = (const float*)d_in[7];
  const float* pos_emb = (const float*)d_in[8];
  const float* ctx_pos = (const float*)d_in[9];
  float* out = (float*)d_out;
  char* ws = (char*)d_ws;

  unsigned short* Wqt = (unsigned short*)(ws);               //   524,288
  unsigned short* Wkt = (unsigned short*)(ws + 524288);
  unsigned short* Wvt = (unsigned short*)(ws + 1048576);
  unsigned short* Wot = (unsigned short*)(ws + 1572864);
  unsigned short* Aq  = (unsigned short*)(ws + 2097152);     // 8,388,608
  unsigned short* Ac  = (unsigned short*)(ws + 10485760);    // 4,194,304
  unsigned short* Qb  = (unsigned short*)(ws + 14680064);    // 8,388,608
  unsigned short* Kb  = (unsigned short*)(ws + 23068672);    // 4,194,304
  unsigned short* Vt  = (unsigned short*)(ws + 27262976);    // 4,194,304
  unsigned short* Abf = (unsigned short*)(ws + 31457280);    // 8,388,608
  int*            prm = (int*)(ws + 39845888);               //    32,768 (end 39,878,656)

  prep_w  <<<256, 256, 0, stream>>>(Wq, Wk, Wv, Wo, Wqt, Wkt, Wvt, Wot);
  prep_in <<<6148, 256, 0, stream>>>(feats, coords, pos_emb, ctx, ctx_pos, Aq, Ac, prm);
  gemm_qkv<<<512, 256, 0, stream>>>(Aq, Ac, Wqt, Wkt, Wvt, Qb, Kb, Vt);
  attn_mfma<<<512, 512, 0, stream>>>(Qb, Kb, Vt, coords, prm, Abf);
  gemm_o  <<<512, 256, 0, stream>>>(Abf, Wot, out, bo);
}

// Round 15
// 80.378 us; speedup vs baseline: 1.5681x; 1.0038x over previous
//
#include <hip/hip_runtime.h>

// B=4, P=2048, N=8192, QD=CD=INNER=512, HEADS=8, DH=64, HC=WC=32, L=1024
// STRIDE=8 -> 17x17 clipped rectangle mask

typedef __attribute__((ext_vector_type(8))) short bf16x8;
typedef __attribute__((ext_vector_type(4))) float f32x4;

#define SCL 0.18033688f   // 0.125 * log2(e): softmax in exp2 domain, folded into Q

__device__ __forceinline__ unsigned short f2bf(float x) {
  union { float f; unsigned int u; } v; v.f = x;
  unsigned int r = v.u + 0x7FFFu + ((v.u >> 16) & 1u);  // RNE
  return (unsigned short)(r >> 16);
}

__device__ __forceinline__ unsigned int pk2bf(float a, float b) {
  return (unsigned)f2bf(a) | ((unsigned)f2bf(b) << 16);
}

__device__ __forceinline__ unsigned int cvtpk(float a, float b) {
  unsigned int r;
  asm("v_cvt_pk_bf16_f32 %0, %1, %2" : "=v"(r) : "v"(a), "v"(b));
  return r;
}

__device__ __forceinline__ float fexp2(float x) {
#if __has_builtin(__builtin_amdgcn_exp2f)
  return __builtin_amdgcn_exp2f(x);
#else
  return exp2f(x);
#endif
}

// async global->LDS, 16B per lane; LDS dest = wave-uniform base + lane*16
__device__ __forceinline__ void gload16(const unsigned short* g, char* l) {
  __builtin_amdgcn_global_load_lds(
      (const __attribute__((address_space(1))) unsigned int*)g,
      (__attribute__((address_space(3))) unsigned int*)l, 16, 0, 0);
}

// LDS tile swizzles: [row][16B-chunk] -> byte offset (XOR involution, both sides)
__device__ __forceinline__ int swzb(int row, int chk) {     // 8-chunk rows (128B)
  return row * 128 + ((chk * 16) ^ ((row & 7) << 4));
}
__device__ __forceinline__ int swz32(int row, int chk) {    // 4-chunk rows (64B)
  return row * 64 + ((chk << 4) ^ ((row & 3) << 4));
}

// ---- prep: weights transpose + input bf16 conversion + per-batch cr sort ----
// bid<256: weight tiles; 256<=bid<6400: inputs; bid>=6400: counting sort (4 batches)
__global__ __launch_bounds__(256) void prep_all(const float* __restrict__ Wq, const float* __restrict__ Wk,
                                                const float* __restrict__ Wv, const float* __restrict__ Wo,
                                                const float* __restrict__ feats,
                                                const int* __restrict__ coords,
                                                const float* __restrict__ pos_emb,
                                                const float* __restrict__ ctx,
                                                const float* __restrict__ ctx_pos,
                                                unsigned short* __restrict__ Wqt, unsigned short* __restrict__ Wkt,
                                                unsigned short* __restrict__ Wvt, unsigned short* __restrict__ Wot,
                                                unsigned short* __restrict__ Aq,
                                                unsigned short* __restrict__ Ac,
                                                int* __restrict__ perm) {
  const int bid = blockIdx.x;
  const int t = threadIdx.x;
  if (bid < 256) {
    __shared__ float tile[64][65];
    const int wsel = bid >> 6, tt = bid & 63;
    const int kt = (tt >> 3) << 6, ntb = (tt & 7) << 6;
    const float* W = (wsel == 0) ? Wq : (wsel == 1) ? Wk : (wsel == 2) ? Wv : Wo;
    unsigned short* Wt = (wsel == 0) ? Wqt : (wsel == 1) ? Wkt : (wsel == 2) ? Wvt : Wot;
#pragma unroll
    for (int p = 0; p < 16; ++p) {
      int e = p * 256 + t;
      int row = e >> 6, col = e & 63;
      tile[row][col] = W[(long)(kt + row) * 512 + ntb + col];
    }
    __syncthreads();
#pragma unroll
    for (int p = 0; p < 16; ++p) {
      int e = p * 256 + t;
      int n = e >> 6, k = e & 63;
      Wt[(long)(ntb + n) * 512 + kt + k] = f2bf(tile[k][n]);
    }
    return;
  }
  if (bid >= 6400) {
    // counting sort of batch bb's 2048 queries by center-row cr (bins 0..32)
    __shared__ int hist[64];
    __shared__ int base[64];
    const int bb = bid - 6400;
    if (t < 64) hist[t] = 0;
    __syncthreads();
    int keys[8];
#pragma unroll
    for (int i = 0; i < 8; ++i) {
      int q = bb * 2048 + t * 8 + i;
      int cr = (int)rintf((float)coords[2 * q] * 0.0625f);
      keys[i] = cr;
      atomicAdd(&hist[cr], 1);
    }
    __syncthreads();
    if (t == 0) {
      int s = 0;
      for (int k2 = 0; k2 < 64; ++k2) { base[k2] = s; s += hist[k2]; }
    }
    __syncthreads();
#pragma unroll
    for (int i = 0; i < 8; ++i) {
      int pos = atomicAdd(&base[keys[i]], 1);
      perm[bb * 2048 + pos] = t * 8 + i;
    }
    return;
  }
  int i = (bid - 256) * 256 + t;             // < 1,572,864
  if (i < 1048576) {
    int e = i << 2;
    int q = e >> 9, k = e & 511;
    int pi = ((coords[2 * q] >> 3) << 6) + (coords[2 * q + 1] >> 3);
    float4 a = *(const float4*)(feats + e);
    float4 p = *(const float4*)(pos_emb + ((size_t)pi << 9) + k);
    uint2 o;
    o.x = pk2bf(a.x + p.x, a.y + p.y);
    o.y = pk2bf(a.z + p.z, a.w + p.w);
    *(uint2*)(Aq + e) = o;
  } else {
    int e = (i - 1048576) << 2;
    int r = e >> 9, k = e & 511;
    float4 a = *(const float4*)(ctx + e);
    float4 p = *(const float4*)(ctx_pos + ((size_t)(r & 1023) << 9) + k);
    uint2 o;
    o.x = pk2bf(a.x + p.x, a.y + p.y);
    o.y = pk2bf(a.z + p.z, a.w + p.w);
    *(uint2*)(Ac + e) = o;
  }
}

// ---- fused Q|K|V projections: 128x128 tile, BK=32, global_load_lds dbuf ----
// bx<256: Q (pre-scaled by SCL). bx>=256: K|V (V transposed d-major, keys
// interleaved within 64-tiles: pos = (j&~63) | ((j&15)<<2) | ((j>>4)&3)).
__global__ __launch_bounds__(256) void gemm_qkv(const unsigned short* __restrict__ Aq,
                                                const unsigned short* __restrict__ Ac,
                                                const unsigned short* __restrict__ Wqt,
                                                const unsigned short* __restrict__ Wkt,
                                                const unsigned short* __restrict__ Wvt,
                                                unsigned short* __restrict__ Qb,
                                                unsigned short* __restrict__ Kb,
                                                unsigned short* __restrict__ Vt) {
  __shared__ char Asf[2][8192];    // 128 rows x 32 k, linear (content swizzled)
  __shared__ char Bsf[2][8192];
  const int t = threadIdx.x, l = t & 63, wv = t >> 6;
  const int wr = (wv >> 1) << 6, wc = (wv & 1) << 6;
  const int orig = blockIdx.x;
  const int bx = (orig & 7) * 64 + (orig >> 3);   // chunked XCD swizzle (512 wgs)
  const bool isQ = bx < 256;
  long tm; const unsigned short* Bt; const unsigned short* Ab; bool isV = false; int nt;
  if (isQ) {
    tm = (long)(bx >> 2) * 128;
    nt = bx & 3;
    Bt = Wqt + (long)nt * 65536;
    Ab = Aq;
  } else {
    const int kvx = bx - 256;
    tm = (long)(kvx >> 3) * 128;
    const int y = kvx & 7;
    isV = y >= 4; nt = y & 3;
    Bt = (isV ? Wvt : Wkt) + (long)nt * 65536;
    Ab = Ac;
  }

  // staging: slots i*256 + wv*64 + l; row = slot>>2, dest chunk = l&3,
  // source chunk XOR-preswizzled so swz32 reads come back correct
  auto STAGE = [&](int buf, int k0) {
#pragma unroll
    for (int i = 0; i < 2; ++i) {
      int row = i * 64 + wv * 16 + (l >> 2);
      int chs = (l & 3) ^ (row & 3);
      char* dst = &(Asf[buf][i * 4096 + wv * 1024]);
      gload16(Ab + (tm + row) * 512 + k0 + chs * 8, dst);
      char* dstB = &(Bsf[buf][i * 4096 + wv * 1024]);
      gload16(Bt + (long)row * 512 + k0 + chs * 8, dstB);
    }
  };

  STAGE(0, 0);
  __syncthreads();                                 // drains vmcnt

  f32x4 acc[4][4] = {};
  const int lr = l & 15, g = l >> 4;

  for (int s = 0; s < 16; ++s) {
    const int cur = s & 1;
    if (s < 15) STAGE(cur ^ 1, (s + 1) << 5);      // async, flies under MFMA
    bf16x8 af[4], bfr[4];
#pragma unroll
    for (int i = 0; i < 4; ++i) {
      af[i]  = *(const bf16x8*)(Asf[cur] + swz32(wr + i * 16 + lr, g));
      bfr[i] = *(const bf16x8*)(Bsf[cur] + swz32(wc + i * 16 + lr, g));
    }
#pragma unroll
    for (int mi = 0; mi < 4; ++mi)
#pragma unroll
      for (int ni = 0; ni < 4; ++ni)
        acc[mi][ni] = __builtin_amdgcn_mfma_f32_16x16x32_bf16(af[mi], bfr[ni], acc[mi][ni], 0, 0, 0);
    __syncthreads();                               // also drains prefetch vmcnt
  }

  const int lq = g << 2;
#pragma unroll
  for (int mi = 0; mi < 4; ++mi)
#pragma unroll
    for (int ni = 0; ni < 4; ++ni) {
      int cn = nt * 128 + wc + ni * 16 + lr;
      long r0 = tm + wr + mi * 16 + lq;
      if (isQ) {
#pragma unroll
        for (int r = 0; r < 4; ++r)
          Qb[(r0 + r) * 512 + cn] = f2bf(acc[mi][ni][r] * SCL);
      } else if (!isV) {
#pragma unroll
        for (int r = 0; r < 4; ++r)
          Kb[(r0 + r) * 512 + cn] = f2bf(acc[mi][ni][r]);
      } else {
        int h = cn >> 6, d = cn & 63;
#pragma unroll
        for (int r = 0; r < 4; ++r) {
          long row = r0 + r;
          int b = (int)(row >> 10), j = (int)(row & 1023);
          int jp = (j & ~63) | ((j & 15) << 2) | ((j >> 4) & 3);
          Vt[((long)(b * 8 + h) * 64 + d) * 1024 + jp] = f2bf(acc[mi][ni][r]);
        }
      }
    }
}

// ---- MFMA masked flash attention: 8 waves x 16 sorted q-rows, wave-range skip ----
__global__ __launch_bounds__(512, 4) void attn_mfma(const unsigned short* __restrict__ Qb,
                                                    const unsigned short* __restrict__ Kb,
                                                    const unsigned short* __restrict__ Vt,
                                                    const int* __restrict__ coords,
                                                    const int* __restrict__ perm,
                                                    unsigned short* __restrict__ Abf) {
  __shared__ char Kl[2][8192];                 // 64 keys x 64 d (swizzled)
  __shared__ char Vl[2][8192];                 // 64 d x 64 keys' (swizzled, interleaved)
  __shared__ char Ol[2048];                    // 16 x 64: row0 = ones (row-sum column)
  __shared__ unsigned short Plds[8][16][72];   // per-wave P (col' = 4*lc + kf)
  __shared__ int permL[128];
  __shared__ int rng[2];
  const int t = threadIdx.x, w = t >> 6, l = t & 63;
  const int g = l >> 4, lc = l & 15;
  const int orig = blockIdx.x;
  const int sw = (orig & 7) * 64 + (orig >> 3);    // chunked XCD swizzle (512 wgs)
  const int qx = sw & 15, bh = sw >> 4;
  const int b = bh >> 3, h = bh & 7;

  if (t < 128) permL[t] = perm[b * 2048 + qx * 128 + t];
  if (t == 0) { rng[0] = 63; rng[1] = 0; }
  __syncthreads();

  int rm[4], cm[4];
  int lrmin = 63, lrmax = 0;
#pragma unroll
  for (int r = 0; r < 4; ++r) {
    long qq = (long)b * 2048 + permL[w * 16 + g * 4 + r];
    int cr = (int)rintf((float)coords[2 * qq] * 0.0625f);      // round-half-even = jnp.round
    int cc = (int)rintf((float)coords[2 * qq + 1] * 0.0625f);
    int rlo = max(0, cr - 8), rhi = min(31, cr + 8);
    int clo = max(0, cc - 8), chi = min(31, cc + 8);
    rm[r] = (int)((((unsigned)1 << (rhi - rlo + 1)) - 1) << rlo);
    cm[r] = (int)((((unsigned)1 << (chi - clo + 1)) - 1) << clo);
    lrmin = min(lrmin, rlo); lrmax = max(lrmax, rhi);
  }
#pragma unroll
  for (int off = 32; off > 0; off >>= 1) {
    lrmin = min(lrmin, __shfl_xor(lrmin, off));
    lrmax = max(lrmax, __shfl_xor(lrmax, off));
  }
  const int wt0 = lrmin >> 1, wt1 = lrmax >> 1;
  if (l == 0) { atomicMin(&rng[0], lrmin); atomicMax(&rng[1], lrmax); }

  bf16x8 qfr[2];
  {
    long qrow = (long)b * 2048 + permL[w * 16 + lc];
#pragma unroll
    for (int dc = 0; dc < 2; ++dc)
      qfr[dc] = *(const bf16x8*)(Qb + qrow * 512 + h * 64 + dc * 32 + g * 8);
  }

  const int srow = t >> 3, schk = t & 7;
  const unsigned short* Kg = Kb + ((long)b * 1024) * 512 + h * 64;
  const unsigned short* Vg = Vt + ((long)bh * 64) * 1024;

  if (t < 128) {
    int r = t >> 3, c = t & 7;
    unsigned short vv = (r == 0) ? (unsigned short)0x3F80 : (unsigned short)0;
    unsigned short tmp[8] = {vv, vv, vv, vv, vv, vv, vv, vv};
    *(int4*)(Ol + swzb(r, c)) = *(int4*)tmp;
  }
  __syncthreads();
  const int t0 = rng[0] >> 1, t1 = rng[1] >> 1;
  {
    const int kb0 = t0 * 64;
    int4 sk = *(const int4*)(Kg + (long)(kb0 + srow) * 512 + schk * 8);
    int4 sv_ = *(const int4*)(Vg + (long)srow * 1024 + kb0 + schk * 8);
    *(int4*)(Kl[0] + swzb(srow, schk)) = sk;
    *(int4*)(Vl[0] + swzb(srow, schk)) = sv_;
  }
  __syncthreads();

  f32x4 po[5] = {};

  for (int kt = t0; kt <= t1; ++kt) {
    const int cur = (kt - t0) & 1;
    const int kb = kt * 64;
    int4 nk = {}, nv = {};
    if (kt < t1) {
      const int kbn = kb + 64;
      nk = *(const int4*)(Kg + (long)(kbn + srow) * 512 + schk * 8);
      nv = *(const int4*)(Vg + (long)srow * 1024 + kbn + schk * 8);
    }

    if (kt >= wt0 && kt <= wt1) {          // wave-uniform skip outside own range
      bf16x8 kfr[4][2];
#pragma unroll
      for (int kf = 0; kf < 4; ++kf)
#pragma unroll
        for (int dc = 0; dc < 2; ++dc)
          kfr[kf][dc] = *(const bf16x8*)(Kl[cur] + swzb(kf * 16 + lc, dc * 4 + g));

      f32x4 sv[4];
      __builtin_amdgcn_s_setprio(1);
#pragma unroll
      for (int kf = 0; kf < 4; ++kf) {
        f32x4 a = {};
        a = __builtin_amdgcn_mfma_f32_16x16x32_bf16(qfr[0], kfr[kf][0], a, 0, 0, 0);
        a = __builtin_amdgcn_mfma_f32_16x16x32_bf16(qfr[1], kfr[kf][1], a, 0, 0, 0);
        sv[kf] = a;
      }
      __builtin_amdgcn_s_setprio(0);

      const int jrb = kb >> 5;
      int cmk[4][4];
#pragma unroll
      for (int kf = 0; kf < 4; ++kf) {
        int jr = jrb + (kf >> 1);
#pragma unroll
        for (int r = 0; r < 4; ++r)
          cmk[kf][r] = ((rm[r] >> jr) & 1) ? cm[r] : 0;
      }
#pragma unroll
      for (int kf = 0; kf < 4; ++kf) {
        int jc = ((kf & 1) << 4) + lc;
#pragma unroll
        for (int r = 0; r < 4; ++r) {
          float p = fexp2(sv[kf][r]);
          sv[kf][r] = ((cmk[kf][r] >> jc) & 1) ? p : 0.0f;
        }
      }

      bf16x8 vfr[5][2];
#pragma unroll
      for (int df = 0; df < 4; ++df)
#pragma unroll
        for (int kc = 0; kc < 2; ++kc)
          vfr[df][kc] = *(const bf16x8*)(Vl[cur] + swzb(df * 16 + lc, kc * 4 + g));
#pragma unroll
      for (int kc = 0; kc < 2; ++kc)
        vfr[4][kc] = *(const bf16x8*)(Ol + swzb(lc, kc * 4 + g));

#pragma unroll
      for (int r = 0; r < 4; ++r) {
        uint2 pk;
        pk.x = cvtpk(sv[0][r], sv[1][r]);
        pk.y = cvtpk(sv[2][r], sv[3][r]);
        *(uint2*)(&Plds[w][g * 4 + r][4 * lc]) = pk;
      }

      bf16x8 pa0 = *(const bf16x8*)(&Plds[w][lc][g * 8]);
      bf16x8 pa1 = *(const bf16x8*)(&Plds[w][lc][32 + g * 8]);
      __builtin_amdgcn_s_setprio(1);
#pragma unroll
      for (int df = 0; df < 5; ++df) {
        po[df] = __builtin_amdgcn_mfma_f32_16x16x32_bf16(pa0, vfr[df][0], po[df], 0, 0, 0);
        po[df] = __builtin_amdgcn_mfma_f32_16x16x32_bf16(pa1, vfr[df][1], po[df], 0, 0, 0);
      }
      __builtin_amdgcn_s_setprio(0);
    }

    if (kt < t1) {
      const int nxt = cur ^ 1;
      *(int4*)(Kl[nxt] + swzb(srow, schk)) = nk;
      *(int4*)(Vl[nxt] + swzb(srow, schk)) = nv;
    }
    __syncthreads();
  }

#pragma unroll
  for (int r = 0; r < 4; ++r) {
    float lsum = __shfl(po[4][r], l & 48);
    float inv = 1.0f / lsum;
    long qr = (long)b * 2048 + permL[w * 16 + g * 4 + r];
#pragma unroll
    for (int df = 0; df < 4; ++df)
      Abf[qr * 512 + h * 64 + df * 16 + lc] = f2bf(po[df][r] * inv);
  }
}

// ---- output projection: 64x128 tile, BK=32, global_load_lds dbuf ----
__global__ __launch_bounds__(256) void gemm_o(const unsigned short* __restrict__ A,
                                              const unsigned short* __restrict__ Bt,
                                              float* __restrict__ C,
                                              const float* __restrict__ bias) {
  __shared__ char Asf[2][4096];    // 64 rows x 32 k, linear (content swizzled)
  __shared__ char Bsf[2][8192];    // 128 rows x 32 k
  const int t = threadIdx.x, l = t & 63, wv = t >> 6;
  const int wr = (wv >> 1) << 5;
  const int wc = (wv & 1) << 6;
  const int orig = blockIdx.x;
  const int bx = (orig & 7) * 64 + (orig >> 3);    // chunked XCD swizzle (512 wgs)
  const long tm = (long)(bx >> 2) * 64;
  const long tn = (long)(bx & 3) * 128;

  auto STAGE = [&](int buf, int k0) {
    {
      int row = wv * 16 + (l >> 2);                // A: 64 rows x 4 chunks, 1 issue
      int chs = (l & 3) ^ (row & 3);
      char* dst = &(Asf[buf][wv * 1024]);
      gload16(A + (tm + row) * 512 + k0 + chs * 8, dst);
    }
#pragma unroll
    for (int i = 0; i < 2; ++i) {                  // B: 128 rows x 4 chunks, 2 issues
      int row = i * 64 + wv * 16 + (l >> 2);
      int chs = (l & 3) ^ (row & 3);
      char* dst = &(Bsf[buf][i * 4096 + wv * 1024]);
      gload16(Bt + (tn + row) * 512 + k0 + chs * 8, dst);
    }
  };

  STAGE(0, 0);
  __syncthreads();

  f32x4 acc[2][4] = {};
  const int lr = l & 15, g = l >> 4;

  for (int s = 0; s < 16; ++s) {
    const int cur = s & 1;
    if (s < 15) STAGE(cur ^ 1, (s + 1) << 5);
    bf16x8 af[2], bfr[4];
#pragma unroll
    for (int i = 0; i < 2; ++i)
      af[i] = *(const bf16x8*)(Asf[cur] + swz32(wr + i * 16 + lr, g));
#pragma unroll
    for (int i = 0; i < 4; ++i)
      bfr[i] = *(const bf16x8*)(Bsf[cur] + swz32(wc + i * 16 + lr, g));
#pragma unroll
    for (int mi = 0; mi < 2; ++mi)
#pragma unroll
      for (int ni = 0; ni < 4; ++ni)
        acc[mi][ni] = __builtin_amdgcn_mfma_f32_16x16x32_bf16(af[mi], bfr[ni], acc[mi][ni], 0, 0, 0);
    __syncthreads();
  }

  const int lq = g << 2;
#pragma unroll
  for (int mi = 0; mi < 2; ++mi)
#pragma unroll
    for (int ni = 0; ni < 4; ++ni) {
      long col = tn + wc + ni * 16 + lr;
      float bv = bias[col];
      long r0 = tm + wr + mi * 16 + lq;
#pragma unroll
      for (int r = 0; r < 4; ++r)
        C[(r0 + r) * 512 + col] = acc[mi][ni][r] + bv;
    }
}

extern "C" void kernel_launch(void* const* d_in, const int* in_sizes, int n_in,
                              void* d_out, int out_size, void* d_ws, size_t ws_size,
                              hipStream_t stream) {
  (void)in_sizes; (void)n_in; (void)out_size; (void)ws_size;
  const float* feats   = (const float*)d_in[0];
  const int*   coords  = (const int*)d_in[1];
  const float* ctx     = (const float*)d_in[2];
  const float* Wq      = (const float*)d_in[3];
  const float* Wk      = (const float*)d_in[4];
  const float* Wv      = (const float*)d_in[5];
  const float* Wo      = (const float*)d_in[6];
  const float* bo      = (const float*)d_in[7];
  const float* pos_emb = (const float*)d_in[8];
  const float* ctx_pos = (const float*)d_in[9];
  float* out = (float*)d_out;
  char* ws = (char*)d_ws;

  unsigned short* Wqt = (unsigned short*)(ws);               //   524,288
  unsigned short* Wkt = (unsigned short*)(ws + 524288);
  unsigned short* Wvt = (unsigned short*)(ws + 1048576);
  unsigned short* Wot = (unsigned short*)(ws + 1572864);
  unsigned short* Aq  = (unsigned short*)(ws + 2097152);     // 8,388,608
  unsigned short* Ac  = (unsigned short*)(ws + 10485760);    // 4,194,304
  unsigned short* Qb  = (unsigned short*)(ws + 14680064);    // 8,388,608
  unsigned short* Kb  = (unsigned short*)(ws + 23068672);    // 4,194,304
  unsigned short* Vt  = (unsigned short*)(ws + 27262976);    // 4,194,304
  unsigned short* Abf = (unsigned short*)(ws + 31457280);    // 8,388,608
  int*            prm = (int*)(ws + 39845888);               //    32,768 (end 39,878,656)

  prep_all<<<6404, 256, 0, stream>>>(Wq, Wk, Wv, Wo, feats, coords, pos_emb, ctx, ctx_pos,
                                     Wqt, Wkt, Wvt, Wot, Aq, Ac, prm);
  gemm_qkv<<<512, 256, 0, stream>>>(Aq, Ac, Wqt, Wkt, Wvt, Qb, Kb, Vt);
  attn_mfma<<<512, 512, 0, stream>>>(Qb, Kb, Vt, coords, prm, Abf);
  gemm_o  <<<512, 256, 0, stream>>>(Abf, Wot, out, bo);
}